// Round 5
// baseline (1149.746 us; speedup 1.0000x reference)
//
#include <hip/hip_runtime.h>

typedef __attribute__((ext_vector_type(8))) short bf16x8;
typedef __attribute__((ext_vector_type(4))) float f32x4;

#define HID 64
#define TSTEPS 256
#define BATCH 4096
#define BT 16
#define RST 1024          // bytes per LDS row
// byte-column regions within each 1024-B row (each 128-B aligned, 2 slots x 128 B):
#define XOFF  0           // x: 32 bf16 cols used per slot
#define H0OFF 256
#define H1OFF 512
#define H2OFF 768

__device__ __forceinline__ float frcp(float x){ return __builtin_amdgcn_rcpf(x); }
__device__ __forceinline__ float fexp2(float x){ return __builtin_amdgcn_exp2f(x); }

__device__ __forceinline__ ushort f2bf(float f){
  unsigned u = __float_as_uint(f);
  u += 0x7fff + ((u>>16)&1);
  return (ushort)(u>>16);
}
__device__ __forceinline__ float bf2f(ushort u){ return __uint_as_float(((unsigned)u)<<16); }
__device__ __forceinline__ unsigned cvtpk(float lo, float hi){
  unsigned r;
  asm("v_cvt_pk_bf16_f32 %0, %1, %2" : "=v"(r) : "v"(lo), "v"(hi));
  return r;
}

// Weights pre-scaled by log2(e) (gates i,f,o) / 2*log2(e) (gate g) so the
// elementwise path uses bare v_exp_f32 (2^x) with free negate modifiers.
template<int KS>
__device__ __forceinline__ void load_wb(const float* __restrict__ Wih,
    const float* __restrict__ Whh, const float* __restrict__ bih,
    const float* __restrict__ bhh, bf16x8 (&wf)[KS][4], float (&bv)[4],
    int s, int l15, int lhi){
  const int IN = KS*32 - 64;   // 32 (layer0) or 64
  const float L2E = 1.4426950408889634f;
  #pragma unroll
  for (int g = 0; g < 4; ++g){
    const float sc = (g == 2) ? 2.f*L2E : L2E;
    int n = g*64 + s*16 + l15;            // gate column (B col = lane&15)
    bv[g] = (bih[n] + bhh[n]) * sc;
    #pragma unroll
    for (int kt = 0; kt < KS; ++kt){
      int kb = kt*32 + lhi*8;             // same kappa(lane,j) as A-frag reads
      const float* src = (kb < IN) ? (Wih + (size_t)n*IN + kb)
                                   : (Whh + (size_t)n*64 + (kb - IN));
      bf16x8 v;
      #pragma unroll
      for (int j = 0; j < 8; ++j) v[j] = (short)f2bf(src[j] * sc);
      wf[kt][g] = v;
    }
  }
}

// Two cells (C/D rows HR, HR+1) of the merged-denominator LSTM update.
// 5 exp2 + 2 rcp per cell; HR is compile-time so acc indexing stays in regs.
template<int HR>
__device__ __forceinline__ unsigned ew2(const f32x4 (&A)[4], float (&cst)[2]){
  float h[2];
  #pragma unroll
  for (int rl = 0; rl < 2; ++rl){
    const int r = HR + rl;
    float Ai = fexp2(-A[0][r]);           // e^{-i}
    float Bf = fexp2(-A[1][r]);           // e^{-f}
    float G  = fexp2( A[2][r]);           // e^{2g}
    float O  = fexp2(-A[3][r]);           // e^{-o}
    float a1 = 1.f + Ai, b1 = 1.f + Bf, gp = G + 1.f, gm = G - 1.f;
    float cp = (cst[rl]*a1*gp + b1*gm) * frcp(a1*b1*gp);
    cst[rl] = cp;
    float C2 = fexp2(cp * 2.8853900817779268f);   // e^{2c'}
    h[rl] = (C2 - 1.f) * frcp((1.f + O)*(C2 + 1.f));
  }
  return cvtpk(h[0], h[1]);
}

template<int HR>
__device__ __forceinline__ void ew_block(char* lds, int SLo, bool l0, bool l1, bool l2,
    const f32x4 (&A0)[4], const f32x4 (&A1)[4], const f32x4 (&A2)[4],
    float (&cst0)[2], float (&cst1)[2], float (&cst2)[2], const int (&wH)[2]){
  if (l0){
    unsigned p = ew2<HR>(A0, cst0);
    *reinterpret_cast<ushort*>(lds + wH[0] + H0OFF + SLo) = (ushort)p;
    *reinterpret_cast<ushort*>(lds + wH[1] + H0OFF + SLo) = (ushort)(p >> 16);
  }
  if (l1){
    unsigned p = ew2<HR>(A1, cst1);
    *reinterpret_cast<ushort*>(lds + wH[0] + H1OFF + SLo) = (ushort)p;
    *reinterpret_cast<ushort*>(lds + wH[1] + H1OFF + SLo) = (ushort)(p >> 16);
  }
  if (l2){
    unsigned p = ew2<HR>(A2, cst2);
    *reinterpret_cast<ushort*>(lds + wH[0] + H2OFF + SLo) = (ushort)p;
    *reinterpret_cast<ushort*>(lds + wH[1] + H2OFF + SLo) = (ushort)(p >> 16);
  }
}

// One diagonal: layer0@t=d, layer1@t=d-1, layer2@t=d-2 — all independent,
// reading only previous-diagonal LDS slots. ONE barrier per diagonal.
// All 8 waves do the full MFMA set (partner-duplicated); elementwise is
// split by accumulator row index: halfu=0 -> rows {0,1}, halfu=1 -> {2,3}.
template<int SL, bool L0, bool L1, bool L2>
__device__ __forceinline__ void diag_step(char* lds, int d, int halfu,
    const bf16x8 (&wf0)[3][4], const bf16x8 (&wf1)[4][4], const bf16x8 (&wf2)[4][4],
    const float (&bv0)[4], const float (&bv1)[4], const float (&bv2)[4],
    float (&cst0)[2], float (&cst1)[2], float (&cst2)[2],
    float2 &xr, const float* __restrict__ xbase,
    int rdA, int rdB, const int (&wH)[2], int xwAddr){
  const int RSo = (SL^1)*128;   // previous-diagonal slot (h reads, x stage)
  const int SLo = SL*128;       // current slot (h writes, x read)

  bf16x8 ax, h0a, h0b, h1a, h1b, h2a, h2b;
  if (L0)       ax  = *reinterpret_cast<const bf16x8*>(lds + rdA + XOFF  + SLo);
  if (L0 || L1){ h0a = *reinterpret_cast<const bf16x8*>(lds + rdA + H0OFF + RSo);
                 h0b = *reinterpret_cast<const bf16x8*>(lds + rdB + H0OFF + RSo); }
  if (L1 || L2){ h1a = *reinterpret_cast<const bf16x8*>(lds + rdA + H1OFF + RSo);
                 h1b = *reinterpret_cast<const bf16x8*>(lds + rdB + H1OFF + RSo); }
  if (L2)      { h2a = *reinterpret_cast<const bf16x8*>(lds + rdA + H2OFF + RSo);
                 h2b = *reinterpret_cast<const bf16x8*>(lds + rdB + H2OFF + RSo); }

  f32x4 A0[4], A1[4], A2[4];
  if (L0){
    #pragma unroll
    for (int g = 0; g < 4; ++g){
      f32x4 c = {bv0[g], bv0[g], bv0[g], bv0[g]};
      c = __builtin_amdgcn_mfma_f32_16x16x32_bf16(ax,  wf0[0][g], c, 0, 0, 0);
      c = __builtin_amdgcn_mfma_f32_16x16x32_bf16(h0a, wf0[1][g], c, 0, 0, 0);
      A0[g] = __builtin_amdgcn_mfma_f32_16x16x32_bf16(h0b, wf0[2][g], c, 0, 0, 0);
    }
  }
  if (L1){
    #pragma unroll
    for (int g = 0; g < 4; ++g){
      f32x4 c = {bv1[g], bv1[g], bv1[g], bv1[g]};
      c = __builtin_amdgcn_mfma_f32_16x16x32_bf16(h0a, wf1[0][g], c, 0, 0, 0);
      c = __builtin_amdgcn_mfma_f32_16x16x32_bf16(h0b, wf1[1][g], c, 0, 0, 0);
      c = __builtin_amdgcn_mfma_f32_16x16x32_bf16(h1a, wf1[2][g], c, 0, 0, 0);
      A1[g] = __builtin_amdgcn_mfma_f32_16x16x32_bf16(h1b, wf1[3][g], c, 0, 0, 0);
    }
  }
  if (L2){
    #pragma unroll
    for (int g = 0; g < 4; ++g){
      f32x4 c = {bv2[g], bv2[g], bv2[g], bv2[g]};
      c = __builtin_amdgcn_mfma_f32_16x16x32_bf16(h1a, wf2[0][g], c, 0, 0, 0);
      c = __builtin_amdgcn_mfma_f32_16x16x32_bf16(h1b, wf2[1][g], c, 0, 0, 0);
      c = __builtin_amdgcn_mfma_f32_16x16x32_bf16(h2a, wf2[2][g], c, 0, 0, 0);
      A2[g] = __builtin_amdgcn_mfma_f32_16x16x32_bf16(h2b, wf2[3][g], c, 0, 0, 0);
    }
  }

  if (halfu == 0){                 // wave-uniform branch
    if (L0){   // stage x(d+1) into prev slot; prefetch x(d+2) — waves 0-3 only
      unsigned pk = cvtpk(xr.x, xr.y);
      *reinterpret_cast<unsigned*>(lds + xwAddr + XOFF + RSo) = pk;
      int tn = d + 2; if (tn > TSTEPS-1) tn = TSTEPS-1;
      xr = *reinterpret_cast<const float2*>(xbase + (size_t)tn*32);
    }
    ew_block<0>(lds, SLo, L0, L1, L2, A0, A1, A2, cst0, cst1, cst2, wH);
  } else {
    ew_block<2>(lds, SLo, L0, L1, L2, A0, A1, A2, cst0, cst1, cst2, wH);
  }
  __syncthreads();
}

__global__ __launch_bounds__(512, 2) void lstm3_wave_kernel(
    const float* __restrict__ x,
    const float* Wih0, const float* Whh0, const float* bih0, const float* bhh0,
    const float* Wih1, const float* Whh1, const float* bih1, const float* bhh1,
    const float* Wih2, const float* Whh2, const float* bih2, const float* bhh2,
    const float* __restrict__ fc1w, const float* __restrict__ fc1b,
    const float* __restrict__ fc2w, const float* __restrict__ fc2b,
    float* __restrict__ out){
  __shared__ char lds[BT*RST];
  __shared__ float fcbuf[BT*16];

  const int tid   = threadIdx.x;
  const int lane  = tid & 63;
  const int wid   = tid >> 6;       // 0..7
  const int s     = wid & 3;        // hidden col-slice (16 cols)
  const int halfu = wid >> 2;       // 0: ew rows {0,1}, 1: ew rows {2,3}
  const int l15   = lane & 15;
  const int lhi   = lane >> 4;
  const int row0  = blockIdx.x * BT;

  bf16x8 wf0[3][4], wf1[4][4], wf2[4][4];
  float bv0[4], bv1[4], bv2[4];
  load_wb<3>(Wih0, Whh0, bih0, bhh0, wf0, bv0, s, l15, lhi);
  load_wb<4>(Wih1, Whh1, bih1, bhh1, wf1, bv1, s, l15, lhi);
  load_wb<4>(Wih2, Whh2, bih2, bhh2, wf2, bv2, s, l15, lhi);

  // Precomputed swizzled LDS addresses (XOR swizzle: byte ^= (row&7)<<4,
  // stays within each 128-B region; slots/regions are +imm offsets).
  const int rdA = l15*RST + ((lhi*16) ^ ((l15 & 7) << 4)); // A-frag, k-tile 0
  const int rdB = rdA ^ 64;                                 // A-frag, k-tile 1
  int wH[2];
  #pragma unroll
  for (int rl = 0; rl < 2; ++rl){
    int row = lhi*4 + halfu*2 + rl;                         // C/D row = batch row
    wH[rl] = row*RST + (((s*16 + l15)*2) ^ ((row & 7) << 4));
  }
  const int xrow = (tid & 255) >> 4;
  const int xwAddr = xrow*RST + ((((tid & 15))*4) ^ ((xrow & 7) << 4));
  const float* xbase = x + ((size_t)(row0 + xrow)*TSTEPS)*32 + (tid & 15)*2;

  // zero all LDS (h(-1)=0 both slots), then stage x(0) into slot 0
  #pragma unroll
  for (int i = 0; i < 2; ++i)
    *reinterpret_cast<int4*>(lds + (tid + i*512)*16) = make_int4(0, 0, 0, 0);
  __syncthreads();
  float2 xr = make_float2(0.f, 0.f);
  if (halfu == 0){
    float2 v0 = *reinterpret_cast<const float2*>(xbase);
    *reinterpret_cast<unsigned*>(lds + xwAddr + XOFF) = cvtpk(v0.x, v0.y);
    xr = *reinterpret_cast<const float2*>(xbase + 32);      // x(1)
  }
  __syncthreads();

  float cst0[2] = {0,0}, cst1[2] = {0,0}, cst2[2] = {0,0};

  #define ARGS lds, d, halfu, wf0, wf1, wf2, bv0, bv1, bv2, cst0, cst1, cst2, \
               xr, xbase, rdA, rdB, wH, xwAddr
  { int d = 0; diag_step<0, true, false, false>(ARGS); }
  { int d = 1; diag_step<1, true, true,  false>(ARGS); }
  for (int d = 2; d < 256; d += 2){
    diag_step<0, true, true, true>(ARGS);
    ++d;
    diag_step<1, true, true, true>(ARGS);
    --d;
  }
  { int d = 256; diag_step<0, false, true,  true>(ARGS); }
  { int d = 257; diag_step<1, false, false, true>(ARGS); }
  #undef ARGS

  // ---- fused FC head: final h2(255) is in H2 slot 1 (diag 257, SL=1) ----
  if (tid < 256){
    const int row  = tid & 15;
    const int slot = tid >> 4;
    const int rx   = (row & 7) << 4;
    float hv[HID];
    #pragma unroll
    for (int i = 0; i < HID; ++i)
      hv[i] = bf2f(*reinterpret_cast<const ushort*>(
                   lds + row*RST + (H2OFF + 128) + ((i*2) ^ rx)));
    float p = 0.f;
    #pragma unroll
    for (int jj = 0; jj < 2; ++jj){
      int j = slot*2 + jj;
      float z = fc1b[j];
      #pragma unroll
      for (int i = 0; i < HID; ++i) z += hv[i]*fc1w[j*HID + i];
      z = fmaxf(z, 0.f);
      p += z * fc2w[j];
    }
    fcbuf[row*16 + slot] = p;
  }
  __syncthreads();
  if (tid < BT){
    float s2 = fc2b[0];
    #pragma unroll
    for (int k = 0; k < 16; ++k) s2 += fcbuf[tid*16 + k];
    out[row0 + tid] = s2;
  }
}

extern "C" void kernel_launch(void* const* d_in, const int* in_sizes, int n_in,
                              void* d_out, int out_size, void* d_ws, size_t ws_size,
                              hipStream_t stream){
  const float* x    = (const float*)d_in[0];
  const float* Wih0 = (const float*)d_in[1];
  const float* Whh0 = (const float*)d_in[2];
  const float* bih0 = (const float*)d_in[3];
  const float* bhh0 = (const float*)d_in[4];
  const float* Wih1 = (const float*)d_in[5];
  const float* Whh1 = (const float*)d_in[6];
  const float* bih1 = (const float*)d_in[7];
  const float* bhh1 = (const float*)d_in[8];
  const float* Wih2 = (const float*)d_in[9];
  const float* Whh2 = (const float*)d_in[10];
  const float* bih2 = (const float*)d_in[11];
  const float* bhh2 = (const float*)d_in[12];
  const float* fc1w = (const float*)d_in[13];
  const float* fc1b = (const float*)d_in[14];
  const float* fc2w = (const float*)d_in[15];
  const float* fc2b = (const float*)d_in[16];

  lstm3_wave_kernel<<<BATCH/BT, 512, 0, stream>>>(x,
      Wih0, Whh0, bih0, bhh0,
      Wih1, Whh1, bih1, bhh1,
      Wih2, Whh2, bih2, bhh2,
      fc1w, fc1b, fc2w, fc2b, (float*)d_out);
}

// Round 6
// 275.677 us; speedup vs baseline: 4.1706x; 4.1706x over previous
//
#include <hip/hip_runtime.h>

typedef __attribute__((ext_vector_type(8))) short bf16x8;
typedef __attribute__((ext_vector_type(4))) float f32x4;

#define HID 64
#define TSTEPS 256
#define BATCH 4096
#define BT 16
#define RST 1024          // bytes per LDS row
// byte-column regions within each 1024-B row (2 slots x 128 B each):
#define XOFF  0           // x: 32 bf16 cols used per slot
#define H0OFF 256
#define H1OFF 512
#define H2OFF 768

__device__ __forceinline__ float frcp(float x){ return __builtin_amdgcn_rcpf(x); }
__device__ __forceinline__ float fexp2(float x){ return __builtin_amdgcn_exp2f(x); }

__device__ __forceinline__ ushort f2bf(float f){
  unsigned u = __float_as_uint(f);
  u += 0x7fff + ((u>>16)&1);
  return (ushort)(u>>16);
}
__device__ __forceinline__ float bf2f(ushort u){ return __uint_as_float(((unsigned)u)<<16); }
__device__ __forceinline__ unsigned cvtpk(float lo, float hi){
  unsigned r;
  asm("v_cvt_pk_bf16_f32 %0, %1, %2" : "=v"(r) : "v"(lo), "v"(hi));
  return r;
}

// Weights pre-scaled by log2(e) (gates i,f,o) / 2*log2(e) (gate g).
// Runtime layer selection (lw is wave-uniform); kt<nk guard keeps indexing static.
__device__ __forceinline__ void load_wb_rt(const float* __restrict__ Wih,
    const float* __restrict__ Whh, const float* __restrict__ bih,
    const float* __restrict__ bhh, int IN, bf16x8 (&wf)[4][4], float (&bv)[4],
    int s, int l15, int lhi){
  const float L2E = 1.4426950408889634f;
  const int nk = (IN + 64) >> 5;          // 3 (layer0) or 4
  #pragma unroll
  for (int g = 0; g < 4; ++g){
    const float sc = (g == 2) ? 2.f*L2E : L2E;
    int n = g*64 + s*16 + l15;            // gate column (B col = lane&15)
    bv[g] = (bih[n] + bhh[n]) * sc;
    #pragma unroll
    for (int kt = 0; kt < 4; ++kt){
      if (kt < nk){
        int kb = kt*32 + lhi*8;           // same kappa(lane,j) as A-frag reads
        const float* src = (kb < IN) ? (Wih + (size_t)n*IN + kb)
                                     : (Whh + (size_t)n*64 + (kb - IN));
        bf16x8 v;
        #pragma unroll
        for (int j = 0; j < 8; ++j) v[j] = (short)f2bf(src[j] * sc);
        wf[kt][g] = v;
      }
    }
  }
}

// Merged-denominator LSTM cell: 5 exp2 + 2 rcp per cell (pre-scaled gates).
__device__ __forceinline__ void ew4(const f32x4 (&A)[4], float (&cst)[4],
                                    unsigned &p01, unsigned &p23){
  float h[4];
  #pragma unroll
  for (int r = 0; r < 4; ++r){
    float Ai = fexp2(-A[0][r]);           // e^{-i}
    float Bf = fexp2(-A[1][r]);           // e^{-f}
    float G  = fexp2( A[2][r]);           // e^{2g}
    float O  = fexp2(-A[3][r]);           // e^{-o}
    float a1 = 1.f + Ai, b1 = 1.f + Bf, gp = G + 1.f, gm = G - 1.f;
    float cp = (cst[r]*a1*gp + b1*gm) * frcp(a1*b1*gp);
    cst[r] = cp;
    float C2 = fexp2(cp * 2.8853900817779268f);   // e^{2c'}
    h[r] = (C2 - 1.f) * frcp((1.f + O)*(C2 + 1.f));
  }
  p01 = cvtpk(h[0], h[1]);
  p23 = cvtpk(h[2], h[3]);
}

// One diagonal: layer0@t=d, layer1@t=d-1, layer2@t=d-2.
// Wave (s,lw) owns layer lw, col-slice s. All reads from slot RSo (prev
// diagonal), all writes to slot SLo (x-stage to RSo's x region, read-free
// this diagonal) -> ONE barrier per diagonal.
template<int SL, bool L0, bool L1, bool L2>
__device__ __forceinline__ void diag_step(char* lds, int d, int lw,
    const bf16x8 (&wf)[4][4], const float (&bv)[4], float (&cst)[4],
    float2 &xr, const float* __restrict__ xbase,
    int aIn, int aRec, const int (&wA)[4], int xwAddr){
  const int RSo = (SL^1)*128;
  const int SLo = SL*128;
  const bool act = (lw == 0) ? L0 : ((lw == 1) ? L1 : L2);

  if (act){
    bf16x8 t0, t1, t2, t3;
    if (lw == 0){
      t0 = *reinterpret_cast<const bf16x8*>(lds + aIn + SLo);          // x(d)
      t1 = *reinterpret_cast<const bf16x8*>(lds + aRec + RSo);         // h0 kt0
      t2 = *reinterpret_cast<const bf16x8*>(lds + (aRec^64) + RSo);    // h0 kt1
    } else {
      t0 = *reinterpret_cast<const bf16x8*>(lds + aIn + RSo);          // h_{l-1} kt0
      t1 = *reinterpret_cast<const bf16x8*>(lds + (aIn^64) + RSo);     // h_{l-1} kt1
      t2 = *reinterpret_cast<const bf16x8*>(lds + aRec + RSo);         // h_l kt0
      t3 = *reinterpret_cast<const bf16x8*>(lds + (aRec^64) + RSo);    // h_l kt1
    }
    f32x4 A[4];
    #pragma unroll
    for (int g = 0; g < 4; ++g){
      f32x4 c = {bv[g], bv[g], bv[g], bv[g]};
      c = __builtin_amdgcn_mfma_f32_16x16x32_bf16(t0, wf[0][g], c, 0, 0, 0);
      c = __builtin_amdgcn_mfma_f32_16x16x32_bf16(t1, wf[1][g], c, 0, 0, 0);
      A[g] = __builtin_amdgcn_mfma_f32_16x16x32_bf16(t2, wf[2][g], c, 0, 0, 0);
    }
    if (lw != 0){
      #pragma unroll
      for (int g = 0; g < 4; ++g)
        A[g] = __builtin_amdgcn_mfma_f32_16x16x32_bf16(t3, wf[3][g], A[g], 0, 0, 0);
    }

    if (lw == 0){   // stage x(d+1) into prev slot; prefetch x(d+2)
      unsigned pk = cvtpk(xr.x, xr.y);
      *reinterpret_cast<unsigned*>(lds + xwAddr + RSo) = pk;
      int tn = d + 2; if (tn > TSTEPS-1) tn = TSTEPS-1;
      xr = *reinterpret_cast<const float2*>(xbase + (size_t)tn*32);
    }

    unsigned p01, p23;
    ew4(A, cst, p01, p23);
    *reinterpret_cast<ushort*>(lds + wA[0] + SLo) = (ushort)p01;
    *reinterpret_cast<ushort*>(lds + wA[1] + SLo) = (ushort)(p01 >> 16);
    *reinterpret_cast<ushort*>(lds + wA[2] + SLo) = (ushort)p23;
    *reinterpret_cast<ushort*>(lds + wA[3] + SLo) = (ushort)(p23 >> 16);
  }
  __syncthreads();
}

__global__ __launch_bounds__(768, 1) void lstm3_wave_kernel(
    const float* __restrict__ x,
    const float* Wih0, const float* Whh0, const float* bih0, const float* bhh0,
    const float* Wih1, const float* Whh1, const float* bih1, const float* bhh1,
    const float* Wih2, const float* Whh2, const float* bih2, const float* bhh2,
    const float* __restrict__ fc1w, const float* __restrict__ fc1b,
    const float* __restrict__ fc2w, const float* __restrict__ fc2b,
    float* __restrict__ out){
  __shared__ char lds[BT*RST];
  __shared__ float fcbuf[BT*16];

  const int tid  = threadIdx.x;
  const int lane = tid & 63;
  const int wid  = tid >> 6;      // 0..11
  const int s    = wid & 3;       // 16-col hidden slice
  const int lw   = wid >> 2;      // owned layer 0..2
  const int l15  = lane & 15;
  const int lhi  = lane >> 4;
  const int row0 = blockIdx.x * BT;

  // per-wave layer pointers (wave-uniform)
  const float* Wih = (lw == 0) ? Wih0 : ((lw == 1) ? Wih1 : Wih2);
  const float* Whh = (lw == 0) ? Whh0 : ((lw == 1) ? Whh1 : Whh2);
  const float* bih = (lw == 0) ? bih0 : ((lw == 1) ? bih1 : bih2);
  const float* bhh = (lw == 0) ? bhh0 : ((lw == 1) ? bhh1 : bhh2);
  const int IN = (lw == 0) ? 32 : 64;

  bf16x8 wf[4][4];
  float bv[4];
  load_wb_rt(Wih, Whh, bih, bhh, IN, wf, bv, s, l15, lhi);

  // Precomputed swizzled LDS addresses (byte ^= (row&7)<<4 within 128-B region)
  const int rdA  = l15*RST + ((lhi*16) ^ ((l15 & 7) << 4));
  const int aIn  = rdA + ((lw == 0) ? XOFF : ((lw == 1) ? H0OFF : H1OFF));
  const int aRec = rdA + (H0OFF + lw*256);
  int wA[4];
  #pragma unroll
  for (int r = 0; r < 4; ++r){
    int row = lhi*4 + r;                  // C/D row = batch row
    wA[r] = row*RST + (H0OFF + lw*256) + (((s*16 + l15)*2) ^ ((row & 7) << 4));
  }
  const int xrow = (tid & 255) >> 4;
  const int xwAddr = xrow*RST + XOFF + (((tid & 15)*4) ^ ((xrow & 7) << 4));
  const float* xbase = x + ((size_t)(row0 + xrow)*TSTEPS)*32 + (tid & 15)*2;

  // zero LDS (h(-1)=0 both slots): 768*16 + 256*16 = 16384 B
  *reinterpret_cast<int4*>(lds + tid*16) = make_int4(0, 0, 0, 0);
  if (tid < 256)
    *reinterpret_cast<int4*>(lds + 12288 + tid*16) = make_int4(0, 0, 0, 0);
  __syncthreads();
  float2 xr = make_float2(0.f, 0.f);
  if (tid < 256){                         // layer-0 waves stage x(0), hold x(1)
    float2 v0 = *reinterpret_cast<const float2*>(xbase);
    *reinterpret_cast<unsigned*>(lds + xwAddr) = cvtpk(v0.x, v0.y);  // slot 0
    xr = *reinterpret_cast<const float2*>(xbase + 32);
  }
  __syncthreads();

  float cst[4] = {0.f, 0.f, 0.f, 0.f};

  #define ARGS lds, d, lw, wf, bv, cst, xr, xbase, aIn, aRec, wA, xwAddr
  { int d = 0; diag_step<0, true, false, false>(ARGS); }
  { int d = 1; diag_step<1, true, true,  false>(ARGS); }
  for (int d = 2; d < 256; d += 2){
    diag_step<0, true, true, true>(ARGS);
    ++d;
    diag_step<1, true, true, true>(ARGS);
    --d;
  }
  { int d = 256; diag_step<0, false, true,  true>(ARGS); }
  { int d = 257; diag_step<1, false, false, true>(ARGS); }
  #undef ARGS

  // ---- fused FC head: final h2(255) is in H2 slot 1 (diag 257, SL=1) ----
  if (tid < 256){
    const int row  = tid & 15;
    const int slot = tid >> 4;
    const int rx   = (row & 7) << 4;
    float hv[HID];
    #pragma unroll
    for (int i = 0; i < HID; ++i)
      hv[i] = bf2f(*reinterpret_cast<const ushort*>(
                   lds + row*RST + (H2OFF + 128) + ((i*2) ^ rx)));
    float p = 0.f;
    #pragma unroll
    for (int jj = 0; jj < 2; ++jj){
      int j = slot*2 + jj;
      float z = fc1b[j];
      #pragma unroll
      for (int i = 0; i < HID; ++i) z += hv[i]*fc1w[j*HID + i];
      z = fmaxf(z, 0.f);
      p += z * fc2w[j];
    }
    fcbuf[row*16 + slot] = p;
  }
  __syncthreads();
  if (tid < BT){
    float s2 = fc2b[0];
    #pragma unroll
    for (int k = 0; k < 16; ++k) s2 += fcbuf[tid*16 + k];
    out[row0 + tid] = s2;
  }
}

extern "C" void kernel_launch(void* const* d_in, const int* in_sizes, int n_in,
                              void* d_out, int out_size, void* d_ws, size_t ws_size,
                              hipStream_t stream){
  const float* x    = (const float*)d_in[0];
  const float* Wih0 = (const float*)d_in[1];
  const float* Whh0 = (const float*)d_in[2];
  const float* bih0 = (const float*)d_in[3];
  const float* bhh0 = (const float*)d_in[4];
  const float* Wih1 = (const float*)d_in[5];
  const float* Whh1 = (const float*)d_in[6];
  const float* bih1 = (const float*)d_in[7];
  const float* bhh1 = (const float*)d_in[8];
  const float* Wih2 = (const float*)d_in[9];
  const float* Whh2 = (const float*)d_in[10];
  const float* bih2 = (const float*)d_in[11];
  const float* bhh2 = (const float*)d_in[12];
  const float* fc1w = (const float*)d_in[13];
  const float* fc1b = (const float*)d_in[14];
  const float* fc2w = (const float*)d_in[15];
  const float* fc2b = (const float*)d_in[16];

  lstm3_wave_kernel<<<BATCH/BT, 768, 0, stream>>>(x,
      Wih0, Whh0, bih0, bhh0,
      Wih1, Whh1, bih1, bhh1,
      Wih2, Whh2, bih2, bhh2,
      fc1w, fc1b, fc2w, fc2b, (float*)d_out);
}